// Round 14
// baseline (136.554 us; speedup 1.0000x reference)
//
#include <hip/hip_runtime.h>

// SelfAttention: out = softmax((x Wq^T)(x Wk^T)^T / 32) (x Wv^T)
// N=4096, D=1024, f32 in/out; bf16 MFMA compute.
// v14 = r13 (best: 136.5us) + QKV retiled 256x128->128x192:
//   grid 16x32 = 512 blocks = exactly 2 blocks/CU (was 384 = 1.5/CU with a
//   half-empty second dispatch wave). Wave-tile 64x96, 5 staging loads/tile,
//   prefetch-1 + vmcnt(5), same swizzle family. K-order per output unchanged
//   -> bit-identical q/k/vT. S (8-phase 256x256) / PV (256x128) / cast /
//   reduce verbatim from r13.

typedef __attribute__((ext_vector_type(8))) __bf16 bf16x8;
typedef __attribute__((ext_vector_type(4))) float floatx4;

#define GLB_AS __attribute__((address_space(1)))
#define LDS_AS __attribute__((address_space(3)))

static __device__ __forceinline__ unsigned short f2bf_u16(float f) {
  union { float f; unsigned u; } x; x.f = f;
  unsigned r = x.u;
  r += 0x7fffu + ((r >> 16) & 1u);   // RNE
  return (unsigned short)(r >> 16);
}
static __device__ __forceinline__ float bf2f(unsigned short u) {
  union { unsigned u; float f; } x; x.u = ((unsigned)u) << 16; return x.f;
}

// ---------------- cast f32 -> bf16, per-block-uniform source ----------------
__global__ __launch_bounds__(256) void cast_all(const float* __restrict__ x,
                                                const float* __restrict__ Wq,
                                                const float* __restrict__ Wk,
                                                const float* __restrict__ Wv,
                                                unsigned short* __restrict__ xb,
                                                unsigned short* __restrict__ wb) {
  const int b = blockIdx.x;
  const float* src; unsigned short* dst; int k0;
  if (b < 2048)      { src = x;  dst = xb;                   k0 = b * 512; }
  else if (b < 2560) { src = Wq; dst = wb;                   k0 = (b - 2048) * 512; }
  else if (b < 3072) { src = Wk; dst = wb + 1024 * 1024;     k0 = (b - 2560) * 512; }
  else               { src = Wv; dst = wb + 2 * 1024 * 1024; k0 = (b - 3072) * 512; }
#pragma unroll
  for (int j = 0; j < 2; ++j) {
    const int k = k0 + j * 256 + threadIdx.x;
    float4 v = reinterpret_cast<const float4*>(src)[k];
    ushort4 o = make_ushort4(f2bf_u16(v.x), f2bf_u16(v.y), f2bf_u16(v.z), f2bf_u16(v.w));
    reinterpret_cast<ushort4*>(dst)[k] = o;
  }
}

// ================= QKV GEMM: 128x192 tile, 2 blocks/CU exact =================
// A = xb [4096][1024], B = wb [3072][1024]; q,k -> qkb [4096][2048];
// v -> vT [1024][4096] (transposed store). K=1024, BK=32.
__global__ __launch_bounds__(256, 2) void gemm_qkv192(const unsigned short* __restrict__ A,
                                                      const unsigned short* __restrict__ B,
                                                      unsigned short* __restrict__ qkb,
                                                      unsigned short* __restrict__ vT) {
  // LDS: 2 bufs x (A [128][32] + B [192][32]) = 20480 elems = 40 KiB
  __shared__ unsigned short sh[20480];
  const int t = threadIdx.x;
  const int w = t >> 6, lane = t & 63;
  const int wm = w >> 1, wn = w & 1;        // 2x2 waves, wave tile 64x96
  const int gx = gridDim.x;                 // 16
  const int nwg = gx * gridDim.y;           // 512 (%8==0)
  int bid = blockIdx.y * gx + blockIdx.x;
  bid = (bid & 7) * (nwg >> 3) + (bid >> 3);
  const int row0 = (bid / gx) * 128;
  const int col0 = (bid % gx) * 192;
  const int NT = 32;                        // K=1024 / 32

  const int srow = t >> 2;                                  // 0..63
  const int scbe = (((t & 3) ^ ((t >> 3) & 3)) << 3);       // swizzled src col
  const unsigned short* gA0 = A + (size_t)(row0 + srow) * 1024 + scbe;
  const unsigned short* gA1 = gA0 + (size_t)64 * 1024;
  const unsigned short* gB0 = B + (size_t)(col0 + srow) * 1024 + scbe;
  const unsigned short* gB1 = gB0 + (size_t)64 * 1024;
  const unsigned short* gB2 = gB0 + (size_t)128 * 1024;

#define STAGE(tl_) do { \
    const int bb_ = ((tl_) & 1) * 10240; \
    __builtin_amdgcn_global_load_lds((const GLB_AS void*)(gA0 + (tl_) * 32), \
        (LDS_AS void*)&sh[bb_ + t * 8], 16, 0, 0); \
    __builtin_amdgcn_global_load_lds((const GLB_AS void*)(gA1 + (tl_) * 32), \
        (LDS_AS void*)&sh[bb_ + 2048 + t * 8], 16, 0, 0); \
    __builtin_amdgcn_global_load_lds((const GLB_AS void*)(gB0 + (tl_) * 32), \
        (LDS_AS void*)&sh[bb_ + 4096 + t * 8], 16, 0, 0); \
    __builtin_amdgcn_global_load_lds((const GLB_AS void*)(gB1 + (tl_) * 32), \
        (LDS_AS void*)&sh[bb_ + 6144 + t * 8], 16, 0, 0); \
    __builtin_amdgcn_global_load_lds((const GLB_AS void*)(gB2 + (tl_) * 32), \
        (LDS_AS void*)&sh[bb_ + 8192 + t * 8], 16, 0, 0); \
  } while (0)

  const int fr = lane & 15;
  const int sg = (((lane >> 4) ^ ((lane >> 1) & 3)) << 3);
  int aofs[4], bofs[6];
#pragma unroll
  for (int mf = 0; mf < 4; ++mf) aofs[mf] = ((wm * 64 + mf * 16 + fr) << 5) + sg;
#pragma unroll
  for (int nf = 0; nf < 6; ++nf) bofs[nf] = 4096 + ((wn * 96 + nf * 16 + fr) << 5) + sg;

  floatx4 acc[4][6] = {};

  STAGE(0);

  for (int tile = 0; tile < NT; ++tile) {
    if (tile + 1 < NT) {
      STAGE(tile + 1);
      asm volatile("s_waitcnt vmcnt(5)" ::: "memory");   // own tile's 5 loads landed
    } else {
      asm volatile("s_waitcnt vmcnt(0)" ::: "memory");
    }
    __builtin_amdgcn_s_barrier();

    const int bo = (tile & 1) * 10240;
    bf16x8 af[4], bf[6];
#pragma unroll
    for (int mf = 0; mf < 4; ++mf) af[mf] = *(const bf16x8*)&sh[bo + aofs[mf]];
#pragma unroll
    for (int nf = 0; nf < 6; ++nf) bf[nf] = *(const bf16x8*)&sh[bo + bofs[nf]];
    __builtin_amdgcn_s_setprio(1);
#pragma unroll
    for (int mf = 0; mf < 4; ++mf)
#pragma unroll
      for (int nf = 0; nf < 6; ++nf)
        acc[mf][nf] = __builtin_amdgcn_mfma_f32_16x16x32_bf16(af[mf], bf[nf], acc[mf][nf], 0, 0, 0);
    __builtin_amdgcn_s_setprio(0);

    __builtin_amdgcn_s_barrier();
  }
#undef STAGE

  // epilogue: per-nf branch (k|v boundary 2048 is 16-aligned, nf-block single-sided)
  const int er = (lane >> 4) * 4;
  const int ec = lane & 15;
#pragma unroll
  for (int mf = 0; mf < 4; ++mf) {
#pragma unroll
    for (int nf = 0; nf < 6; ++nf) {
      const int n0 = col0 + wn * 96 + nf * 16;
      const int mb = row0 + wm * 64 + mf * 16 + er;
      if (n0 < 2048) {
#pragma unroll
        for (int r = 0; r < 4; ++r)
          qkb[(size_t)(mb + r) * 2048 + (n0 + ec)] = f2bf_u16(acc[mf][nf][r]);
      } else {
        ushort4 o = make_ushort4(f2bf_u16(acc[mf][nf][0]), f2bf_u16(acc[mf][nf][1]),
                                 f2bf_u16(acc[mf][nf][2]), f2bf_u16(acc[mf][nf][3]));
        *reinterpret_cast<ushort4*>(&vT[(size_t)(n0 - 2048 + ec) * 4096 + mb]) = o;
      }
    }
  }
}

// ================= 8-phase 256x256 S-GEMM (verbatim r12/r13) =================
__global__ __launch_bounds__(512, 2) void gemm8p_s(const unsigned short* __restrict__ A,
                                                   const unsigned short* __restrict__ B,
                                                   unsigned short* __restrict__ Pb,
                                                   float* __restrict__ rsp,
                                                   int lda, int ldb, int ldc,
                                                   float scale) {
  __shared__ unsigned short sh[65536];
  const int t = threadIdx.x;
  const int w = t >> 6, lane = t & 63;
  const int wm = w >> 2, wn = w & 3;
  const int gx = gridDim.x;
  const int nwg = gx * gridDim.y;
  int bid = blockIdx.y * gx + blockIdx.x;
  bid = (bid & 7) * (nwg >> 3) + (bid >> 3);
  const int row0 = (bid / gx) * 256;
  const int col0 = (bid % gx) * 256;
  const int NI = 8;

  const int scol = (((t & 7) ^ ((t >> 4) & 7)) << 3);
  const unsigned short* gA = A + (size_t)(row0 + (t >> 3)) * lda + scol;
  const unsigned short* gB = B + (size_t)(col0 + (t >> 3)) * ldb + scol;

#define STG(op_, h_, d_, tl_) do { \
    const unsigned short* s0_ = (op_ ? gB : gA) + \
        (size_t)((h_) * 128) * (op_ ? ldb : lda) + (tl_) * 64; \
    const unsigned short* s1_ = s0_ + (size_t)64 * (op_ ? ldb : lda); \
    unsigned short* l0_ = &sh[(d_) * 32768 + (op_) * 16384 + (h_) * 8192 + t * 8]; \
    __builtin_amdgcn_global_load_lds((const GLB_AS void*)s0_, (LDS_AS void*)l0_, 16, 0, 0); \
    __builtin_amdgcn_global_load_lds((const GLB_AS void*)s1_, (LDS_AS void*)(l0_ + 4096), 16, 0, 0); \
  } while (0)

  const int fr = lane & 15;
  const int lh = lane >> 4;
  const int key = (fr >> 1) & 7;
  const int g0 = ((0 * 4 + lh) ^ key) << 3;
  const int g1 = ((1 * 4 + lh) ^ key) << 3;

  floatx4 acc[8][4] = {};
  bf16x8 afr[4][2], bfr0[2][2], bfr1[2][2];

#define RDA(d_, mh_) do { \
    _Pragma("unroll") for (int mf = 0; mf < 4; ++mf) { \
      const int rb_ = (d_) * 32768 + wm * 8192 + (((mh_) * 64 + mf * 16 + fr) << 6); \
      afr[mf][0] = *(const bf16x8*)&sh[rb_ + g0]; \
      afr[mf][1] = *(const bf16x8*)&sh[rb_ + g1]; } \
  } while (0)
#define RDB(d_, nh_, dst_) do { \
    _Pragma("unroll") for (int nf = 0; nf < 2; ++nf) { \
      const int rb_ = (d_) * 32768 + 16384 + (wn >> 1) * 8192 + \
                      ((((wn & 1) * 64 + (nh_) * 32 + nf * 16 + fr)) << 6); \
      dst_[nf][0] = *(const bf16x8*)&sh[rb_ + g0]; \
      dst_[nf][1] = *(const bf16x8*)&sh[rb_ + g1]; } \
  } while (0)
#define MFMA16(mh_, nh_, bsrc_) do { \
    __builtin_amdgcn_s_setprio(1); \
    _Pragma("unroll") for (int mf = 0; mf < 4; ++mf) \
      _Pragma("unroll") for (int nf = 0; nf < 2; ++nf) { \
        acc[(mh_)*4+mf][(nh_)*2+nf] = __builtin_amdgcn_mfma_f32_16x16x32_bf16(afr[mf][0], bsrc_[nf][0], acc[(mh_)*4+mf][(nh_)*2+nf], 0, 0, 0); \
        acc[(mh_)*4+mf][(nh_)*2+nf] = __builtin_amdgcn_mfma_f32_16x16x32_bf16(afr[mf][1], bsrc_[nf][1], acc[(mh_)*4+mf][(nh_)*2+nf], 0, 0, 0); } \
    __builtin_amdgcn_s_setprio(0); \
  } while (0)
#define BAR()  __builtin_amdgcn_s_barrier()
#define LGKM() do { asm volatile("s_waitcnt lgkmcnt(0)" ::: "memory"); \
                    __builtin_amdgcn_sched_barrier(0); } while (0)

  STG(1, 0, 0, 0); STG(0, 0, 0, 0); STG(1, 1, 0, 0); STG(0, 1, 0, 0);
  STG(1, 0, 1, 1); STG(0, 0, 1, 1);
  asm volatile("s_waitcnt vmcnt(4)" ::: "memory");
  BAR();

  for (int j = 0; j < NI; ++j) {
    const bool more = (j < NI - 1);
    RDA(0, 0); RDB(0, 0, bfr0);
    STG(1, 1, 1, 2 * j + 1);
    BAR(); LGKM(); MFMA16(0, 0, bfr0); BAR();
    RDB(0, 1, bfr1);
    STG(0, 1, 1, 2 * j + 1);
    BAR(); LGKM(); MFMA16(0, 1, bfr1); BAR();
    RDA(0, 1);
    if (more) STG(1, 0, 0, 2 * j + 2);
    BAR(); LGKM(); MFMA16(1, 0, bfr0); BAR();
    if (more) STG(0, 0, 0, 2 * j + 2);
    BAR(); LGKM(); MFMA16(1, 1, bfr1);
    if (j == NI - 1) { asm volatile("s_waitcnt vmcnt(0)" ::: "memory"); }
    else             { asm volatile("s_waitcnt vmcnt(4)" ::: "memory"); }
    BAR();
    RDA(1, 0); RDB(1, 0, bfr0);
    if (more) STG(1, 1, 0, 2 * j + 2);
    BAR(); LGKM(); MFMA16(0, 0, bfr0); BAR();
    RDB(1, 1, bfr1);
    if (more) STG(0, 1, 0, 2 * j + 2);
    BAR(); LGKM(); MFMA16(0, 1, bfr1); BAR();
    RDA(1, 1);
    if (more) STG(1, 0, 1, 2 * j + 3);
    BAR(); LGKM(); MFMA16(1, 0, bfr0); BAR();
    if (more) STG(0, 0, 1, 2 * j + 3);
    BAR(); LGKM(); MFMA16(1, 1, bfr1);
    asm volatile("s_waitcnt vmcnt(4)" ::: "memory");
    BAR();
  }
#undef STG
#undef RDA
#undef RDB
#undef MFMA16
#undef BAR
#undef LGKM

  const int er = (lane >> 4) * 4;
  const int ec = lane & 15;
  const int rj = ((col0 >> 6) + wn) * 4096;
#pragma unroll
  for (int ai = 0; ai < 8; ++ai) {
#pragma unroll
    for (int r = 0; r < 4; ++r) {
      const int m = row0 + wm * 128 + (ai >> 2) * 64 + (ai & 3) * 16 + er + r;
      float rsum = 0.f;
#pragma unroll
      for (int bj = 0; bj < 4; ++bj) {
        const float e = __expf(acc[ai][bj][r] * scale);
        Pb[(size_t)m * ldc + (col0 + wn * 64 + (bj >> 1) * 32 + (bj & 1) * 16 + ec)] = f2bf_u16(e);
        rsum += e;
      }
      rsum += __shfl_xor(rsum, 1);
      rsum += __shfl_xor(rsum, 2);
      rsum += __shfl_xor(rsum, 4);
      rsum += __shfl_xor(rsum, 8);
      if (ec == 0) rsp[rj + m] = rsum;
    }
  }
}

// ================= PV GEMM (verbatim r13, EPI=0 only) =================
struct GemmOuts { void* c[4]; int ldc[4]; };

__global__ __launch_bounds__(256, 2) void gemm_pv(const unsigned short* __restrict__ A,
                                                  const unsigned short* __restrict__ B,
                                                  GemmOuts outs, int lda, int ldb,
                                                  int klen, float scale) {
  __shared__ unsigned short sh[24576];
  const int t = threadIdx.x;
  const int w = t >> 6, lane = t & 63;
  const int wm = w >> 1, wn = w & 1;
  const int gx = gridDim.x;
  const int nwg = gx * gridDim.y;
  int bid = blockIdx.y * gx + blockIdx.x;
  bid = (bid & 7) * (nwg >> 3) + (bid >> 3);
  const int row0 = (bid / gx) * 256;
  const int col0 = (bid % gx) * 128;
  const int z = blockIdx.z;
  const int kstart = z * klen;
  const int NT = klen >> 5;

  const int srow = t >> 2;
  const int scbe = (((t & 3) ^ ((t >> 3) & 3)) << 3);
  const unsigned short* gA0 = A + (size_t)(row0 + srow) * lda + kstart + scbe;
  const unsigned short* gA1 = gA0 + (size_t)64 * lda;
  const unsigned short* gA2 = gA0 + (size_t)128 * lda;
  const unsigned short* gA3 = gA0 + (size_t)192 * lda;
  const unsigned short* gB0 = B + (size_t)(col0 + srow) * ldb + kstart + scbe;
  const unsigned short* gB1 = gB0 + (size_t)64 * ldb;

#define STAGE(tl_) do { \
    const int bb_ = ((tl_) & 1) * 12288; \
    __builtin_amdgcn_global_load_lds((const GLB_AS void*)(gA0 + (tl_) * 32), \
        (LDS_AS void*)&sh[bb_ + t * 8], 16, 0, 0); \
    __builtin_amdgcn_global_load_lds((const GLB_AS void*)(gA1 + (tl_) * 32), \
        (LDS_AS void*)&sh[bb_ + 2048 + t * 8], 16, 0, 0); \
    __builtin_amdgcn_global_load_lds((const GLB_AS void*)(gA2 + (tl_) * 32), \
        (LDS_AS void*)&sh[bb_ + 4096 + t * 8], 16, 0, 0); \
    __builtin_amdgcn_global_load_lds((const GLB_AS void*)(gA3 + (tl_) * 32), \
        (LDS_AS void*)&sh[bb_ + 6144 + t * 8], 16, 0, 0); \
    __builtin_amdgcn_global_load_lds((const GLB_AS void*)(gB0 + (tl_) * 32), \
        (LDS_AS void*)&sh[bb_ + 8192 + t * 8], 16, 0, 0); \
    __builtin_amdgcn_global_load_lds((const GLB_AS void*)(gB1 + (tl_) * 32), \
        (LDS_AS void*)&sh[bb_ + 10240 + t * 8], 16, 0, 0); \
  } while (0)

  const int fr = lane & 15;
  const int sg = (((lane >> 4) ^ ((lane >> 1) & 3)) << 3);
  int aofs[8], bofs[4];
#pragma unroll
  for (int mf = 0; mf < 8; ++mf) aofs[mf] = ((wm * 128 + mf * 16 + fr) << 5) + sg;
#pragma unroll
  for (int nf = 0; nf < 4; ++nf) bofs[nf] = 8192 + ((wn * 64 + nf * 16 + fr) << 5) + sg;

  floatx4 acc[8][4] = {};

  STAGE(0);

  for (int tile = 0; tile < NT; ++tile) {
    if (tile + 1 < NT) {
      STAGE(tile + 1);
      asm volatile("s_waitcnt vmcnt(6)" ::: "memory");
    } else {
      asm volatile("s_waitcnt vmcnt(0)" ::: "memory");
    }
    __builtin_amdgcn_s_barrier();

    const int bo = (tile & 1) * 12288;
    bf16x8 af[8], bf[4];
#pragma unroll
    for (int mf = 0; mf < 8; ++mf) af[mf] = *(const bf16x8*)&sh[bo + aofs[mf]];
#pragma unroll
    for (int nf = 0; nf < 4; ++nf) bf[nf] = *(const bf16x8*)&sh[bo + bofs[nf]];
    __builtin_amdgcn_s_setprio(1);
#pragma unroll
    for (int mf = 0; mf < 8; ++mf)
#pragma unroll
      for (int nf = 0; nf < 4; ++nf)
        acc[mf][nf] = __builtin_amdgcn_mfma_f32_16x16x32_bf16(af[mf], bf[nf], acc[mf][nf], 0, 0, 0);
    __builtin_amdgcn_s_setprio(0);

    __builtin_amdgcn_s_barrier();
  }
#undef STAGE

  const int er = (lane >> 4) * 4;
  const int ec = lane & 15;
  unsigned short* Cb = (unsigned short*)outs.c[z];
  const int ldc = outs.ldc[z];
#pragma unroll
  for (int mf = 0; mf < 8; ++mf)
#pragma unroll
    for (int nf = 0; nf < 4; ++nf)
#pragma unroll
      for (int r = 0; r < 4; ++r)
        Cb[(size_t)(row0 + wm * 128 + mf * 16 + er + r) * ldc +
           (col0 + wn * 64 + nf * 16 + ec)] = f2bf_u16(acc[mf][nf][r] * scale);
}

// ---------------- reduce: one wave per row ----------------
__global__ __launch_bounds__(256) void reduce_pv(float* __restrict__ out,
                                                 const unsigned short* __restrict__ p0,
                                                 const unsigned short* __restrict__ p1,
                                                 const float* __restrict__ rsp) {
  const int w = threadIdx.x >> 6, lane = threadIdx.x & 63;
  const int row = blockIdx.x * 4 + w;
  float s = rsp[lane * 4096 + row];
#pragma unroll
  for (int off = 32; off >= 1; off >>= 1) s += __shfl_xor(s, off);
  const float inv = 1.0f / s;
#pragma unroll
  for (int j = 0; j < 4; ++j) {
    const int idx = row * 256 + j * 64 + lane;
    ushort4 a = ((const ushort4*)p0)[idx];
    ushort4 b = ((const ushort4*)p1)[idx];
    float4 o;
    o.x = (bf2f(a.x) + bf2f(b.x)) * inv;
    o.y = (bf2f(a.y) + bf2f(b.y)) * inv;
    o.z = (bf2f(a.z) + bf2f(b.z)) * inv;
    o.w = (bf2f(a.w) + bf2f(b.w)) * inv;
    ((float4*)out)[idx] = o;
  }
}

extern "C" void kernel_launch(void* const* d_in, const int* in_sizes, int n_in,
                              void* d_out, int out_size, void* d_ws, size_t ws_size,
                              hipStream_t stream) {
  const float* x  = (const float*)d_in[0];
  const float* Wq = (const float*)d_in[1];
  const float* Wk = (const float*)d_in[2];
  const float* Wv = (const float*)d_in[3];
  float* out = (float*)d_out;

  const int N = 4096, D = 1024;

  // workspace (~80 MB):
  // [0,32)   P bf16 [4096][4096] = exp(scores)
  // [32,48)  qkb bf16 [4096][2048]  (q | k)
  // [48,56)  vT bf16 [1024][4096]
  // [56,64)  xb bf16 [4096][1024]; reused as p0 after QKV
  // [64,70)  wb bf16 [3072][1024]
  // [70,71)  rsp f32 [64][4096]
  // [72,80)  p1 bf16 [4096][1024]
  char* ws = (char*)d_ws;
  unsigned short* P   = (unsigned short*)ws;
  unsigned short* qkb = (unsigned short*)(ws + (32u << 20));
  unsigned short* vT  = (unsigned short*)(ws + (48u << 20));
  unsigned short* xb  = (unsigned short*)(ws + (56u << 20));
  unsigned short* wb  = (unsigned short*)(ws + (64u << 20));
  float*          rsp = (float*)(ws + (70u << 20));
  unsigned short* p0  = xb;
  unsigned short* p1  = (unsigned short*)(ws + (72u << 20));

  // casts (per-block-uniform source)
  cast_all<<<3584, 256, 0, stream>>>(x, Wq, Wk, Wv, xb, wb);

  // qkv = x @ [Wq;Wk;Wv]^T : q,k -> qkb; v -> vT  (128x192 tile, 512 blocks)
  gemm_qkv192<<<dim3(3 * D / 192, N / 128, 1), 256, 0, stream>>>(xb, wb, qkb, vT);

  // P = exp((q @ k^T)/32); rsp = row-sum partials  — 8-phase 256x256 kernel
  gemm8p_s<<<dim3(N / 256, N / 256, 1), 512, 0, stream>>>(qkb, qkb + D, P, rsp,
                                                          2 * D, 2 * D, N, 0.03125f);

  // partials = P @ v, split-K x2 (bf16)
  GemmOuts op;
  op.c[0] = p0; op.ldc[0] = D;
  op.c[1] = p1; op.ldc[1] = D;
  op.c[2] = p0; op.ldc[2] = D;
  op.c[3] = p1; op.ldc[3] = D;
  gemm_pv<<<dim3(D / 128, N / 256, 2), 256, 0, stream>>>(P, vT, op, N, N, N / 2, 1.0f);

  // out = (p0+p1) / rowsum  (one wave per row)
  reduce_pv<<<1024, 256, 0, stream>>>(out, p0, p1, rsp);
}